// Round 10
// baseline (74.253 us; speedup 1.0000x reference)
//
#include <hip/hip_runtime.h>
#include <math.h>

typedef __bf16 bf16;
typedef __bf16 bf16x4 __attribute__((ext_vector_type(4)));
typedef __bf16 bf16x8 __attribute__((ext_vector_type(8)));
typedef float f32x4 __attribute__((ext_vector_type(4)));

#define MFMA16(a,b,c) __builtin_amdgcn_mfma_f32_16x16x32_bf16((a),(b),(c),0,0,0)

static constexpr int HS  = 64;    // head size
static constexpr int SEQ = 2048;  // sequence length
static constexpr int NE  = 1024;  // n_embed
static constexpr int NB  = 8;     // batch

__device__ __forceinline__ bf16x8 cvt8(float4 a, float4 b) {
  bf16x8 r;
  r[0]=(bf16)a.x; r[1]=(bf16)a.y; r[2]=(bf16)a.z; r[3]=(bf16)a.w;
  r[4]=(bf16)b.x; r[5]=(bf16)b.y; r[6]=(bf16)b.z; r[7]=(bf16)b.w;
  return r;
}

// ---- W f32 -> bf16 (Wq pre-scaled by 1/sqrt(64)) ----
__global__ __launch_bounds__(256) void wcvt_kernel(
    const float* __restrict__ Wq, const float* __restrict__ Wk,
    const float* __restrict__ Wv, bf16* __restrict__ wqb,
    bf16* __restrict__ wkb, bf16* __restrict__ wvb)
{
  int i = (blockIdx.x * 256 + threadIdx.x) * 4;   // 64 blocks -> 65536 elems
  float4 q = *(const float4*)(Wq + i);
  float4 k = *(const float4*)(Wk + i);
  float4 v = *(const float4*)(Wv + i);
  bf16x4 qo, ko, vo;
  qo[0]=(bf16)(q.x*0.125f); qo[1]=(bf16)(q.y*0.125f); qo[2]=(bf16)(q.z*0.125f); qo[3]=(bf16)(q.w*0.125f);
  ko[0]=(bf16)k.x; ko[1]=(bf16)k.y; ko[2]=(bf16)k.z; ko[3]=(bf16)k.w;
  vo[0]=(bf16)v.x; vo[1]=(bf16)v.y; vo[2]=(bf16)v.z; vo[3]=(bf16)v.w;
  *(bf16x4*)(wqb + i) = qo;
  *(bf16x4*)(wkb + i) = ko;
  *(bf16x4*)(wvb + i) = vo;
}

// ---- projection: reg-staged, 3-buffer, lgkm-only barriers ----
// Per step t: ds_write buf[(t+1)%3] from regset (vmcnt waits are the
// compiler's PRECISE per-register ones), issue loads for kt t+3 into the
// freed regset, then lgkmcnt(0)+s_barrier (never touches vmcnt), compute
// buf[t%3]. Global-load pipeline is never drained. 72 KB LDS -> 2 blk/CU.
// LDS layout per buffer: [64 rows][8 segs of 16B], seg' = seg ^ (row&7).
template<int KV>
__device__ __forceinline__ void proj_body(
    const float* __restrict__ X, const bf16* __restrict__ W0,
    const bf16* __restrict__ W1, bf16* __restrict__ out0,
    bf16* __restrict__ outVT, int slab,
    char* Xs0, char* Xs1, char* Xs2,
    char* W0s0, char* W0s1, char* W0s2,
    char* W1s0, char* W1s1, char* W1s2)
{
  const int tid  = threadIdx.x;
  const int lane = tid & 63;
  const int w    = tid >> 6;
  const int m    = lane & 15;
  const int g    = lane >> 4;
  const int rowBase = slab * 64;
  const int srow = tid >> 2;            // staging row 0..63
  const int sg2  = (tid & 3) * 2;       // staging seg pair (16B units)

  const float* Xrow  = X  + (size_t)(rowBase + srow) * NE + (tid & 3) * 16;
  const bf16*  W0row = W0 + (size_t)srow * NE + (tid & 3) * 16;
  const bf16*  W1row = KV ? (W1 + (size_t)srow * NE + (tid & 3) * 16) : nullptr;

  const f32x4 vz = {0.f,0.f,0.f,0.f};
  f32x4 accA[4] = {vz, vz, vz, vz};
  f32x4 accB[4] = {vz, vz, vz, vz};     // DCE'd when !KV

  // two named register sets (A: even kt, B: odd kt) — no arrays, no scratch
  float4 xaA, xbA, xcA, xdA;  bf16x8 w0aA, w0bA, w1aA, w1bA;
  float4 xaB, xbB, xcB, xdB;  bf16x8 w0aB, w0bB, w1aB, w1bB;

#define LOAD_SET(S, kt) do {                                          \
    const float* _xp = Xrow + (kt) * 64;                              \
    xa##S = *(const float4*)(_xp);      xb##S = *(const float4*)(_xp + 4);  \
    xc##S = *(const float4*)(_xp + 8);  xd##S = *(const float4*)(_xp + 12); \
    const bf16* _w0 = W0row + (kt) * 64;                              \
    w0a##S = *(const bf16x8*)(_w0);     w0b##S = *(const bf16x8*)(_w0 + 8); \
    if (KV) { const bf16* _w1 = W1row + (kt) * 64;                    \
      w1a##S = *(const bf16x8*)(_w1);   w1b##S = *(const bf16x8*)(_w1 + 8); } \
  } while (0)

#define WRITE_SET(S, Xd, W0d, W1d) do {                               \
    *(bf16x8*)((Xd)  + srow*128 + 16*(( sg2   ) ^ (srow & 7))) = cvt8(xa##S, xb##S); \
    *(bf16x8*)((Xd)  + srow*128 + 16*(( sg2+1 ) ^ (srow & 7))) = cvt8(xc##S, xd##S); \
    *(bf16x8*)((W0d) + srow*128 + 16*(( sg2   ) ^ (srow & 7))) = w0a##S; \
    *(bf16x8*)((W0d) + srow*128 + 16*(( sg2+1 ) ^ (srow & 7))) = w0b##S; \
    if (KV) {                                                          \
      *(bf16x8*)((W1d) + srow*128 + 16*(( sg2   ) ^ (srow & 7))) = w1a##S; \
      *(bf16x8*)((W1d) + srow*128 + 16*(( sg2+1 ) ^ (srow & 7))) = w1b##S; \
    }                                                                  \
  } while (0)

  auto compute = [&](const char* Xd, const char* W0d, const char* W1d) {
#pragma unroll
    for (int kk = 0; kk < 2; ++kk) {
      const int arow = 16*w + m;
      const int s = kk*4 + g;
      bf16x8 af = *(const bf16x8*)(Xd + arow*128 + 16*(s ^ (arow & 7)));
#pragma unroll
      for (int n = 0; n < 4; ++n) {
        const int col = 16*n + m;
        bf16x8 b0 = *(const bf16x8*)(W0d + col*128 + 16*(s ^ (col & 7)));
        accA[n] = MFMA16(af, b0, accA[n]);
        if (KV) {
          bf16x8 b1 = *(const bf16x8*)(W1d + col*128 + 16*(s ^ (col & 7)));
          accB[n] = MFMA16(af, b1, accB[n]);
        }
      }
    }
  };

  char* const XB[3]  = {Xs0,  Xs1,  Xs2};
  char* const W0B[3] = {W0s0, W0s1, W0s2};
  char* const W1B[3] = {W1s0, W1s1, W1s2};

  // prologue: kt0->A, kt1->B, write buf0<-A, reload A<-kt2
  LOAD_SET(A, 0);
  LOAD_SET(B, 1);
  WRITE_SET(A, XB[0], W0B[0], W1B[0]);   // precise vmcnt wait on set A only
  LOAD_SET(A, 2);

#pragma unroll
  for (int t = 0; t < 16; ++t) {
    const int wb = (t + 1) % 3;
    if (t < 15) {
      if (((t + 1) & 1) == 0) WRITE_SET(A, XB[wb], W0B[wb], W1B[wb]);
      else                    WRITE_SET(B, XB[wb], W0B[wb], W1B[wb]);
    }
    if (t + 3 < 16) {
      if (((t + 3) & 1) == 0) LOAD_SET(A, t + 3);
      else                    LOAD_SET(B, t + 3);
    }
    __builtin_amdgcn_sched_barrier(0);
    asm volatile("s_waitcnt lgkmcnt(0)" ::: "memory");  // DS only, NOT vmcnt
    __builtin_amdgcn_s_barrier();
    __builtin_amdgcn_sched_barrier(0);
    compute(XB[t % 3], W0B[t % 3], W1B[t % 3]);
  }
#undef LOAD_SET
#undef WRITE_SET

  // C/D: col = lane&15, row = 4*(lane>>4)+i  [m89-verified]
#pragma unroll
  for (int n = 0; n < 4; ++n)
#pragma unroll
    for (int i = 0; i < 4; ++i) {
      int row = rowBase + 16*w + 4*g + i;
      int h   = 16*n + m;
      out0[(size_t)row * HS + h] = (bf16)accA[n][i];
      if (KV)
        outVT[((size_t)(row >> 11) * HS + h) * SEQ + (row & 2047)] =
            (bf16)accB[n][i];
    }
}

__global__ __launch_bounds__(256, 2) void proj_kernel(
    const float* __restrict__ index, const float* __restrict__ memory,
    const bf16* __restrict__ wqb, const bf16* __restrict__ wkb,
    const bf16* __restrict__ wvb, bf16* __restrict__ qb,
    bf16* __restrict__ kb, bf16* __restrict__ vtb)
{
  __shared__ __align__(16) char Xs0[8192],  Xs1[8192],  Xs2[8192];
  __shared__ __align__(16) char W0s0[8192], W0s1[8192], W0s2[8192];
  __shared__ __align__(16) char W1s0[8192], W1s1[8192], W1s2[8192]; // 72 KB
  if (blockIdx.x < 256)
    proj_body<0>(index,  wqb, nullptr, qb, nullptr, blockIdx.x,
                 Xs0, Xs1, Xs2, W0s0, W0s1, W0s2, W1s0, W1s1, W1s2);
  else
    proj_body<1>(memory, wkb, wvb,     kb, vtb, blockIdx.x - 256,
                 Xs0, Xs1, Xs2, W0s0, W0s1, W0s2, W1s0, W1s1, W1s2);
}

// ---- flash attention: swapped-operand softmax (T12), unchanged from R9 ----
__global__ __launch_bounds__(128) void attn_kernel(
    const bf16* __restrict__ qb, const bf16* __restrict__ kb,
    const bf16* __restrict__ vtb, float* __restrict__ out)
{
  __shared__ __align__(16) bf16 Ks[2][64][72];    // per-wave K tile [kv][d]
  __shared__ __align__(16) bf16 VTs[2][64][72];   // per-wave V^T tile [d][kv]
  __shared__ __align__(16) bf16 Ps[2][16][72];    // per-wave P [q][kv]

  const int tid  = threadIdx.x;
  const int lane = tid & 63;
  const int w    = tid >> 6;
  const int m    = lane & 15;
  const int g    = lane >> 4;
  const int qt   = 127 - blockIdx.x;   // reversed: longest blocks first
  const int b    = blockIdx.y;
  const int nkv  = (qt >> 2) + 1;
  const int r0   = lane >> 1;
  const int hh   = (lane & 1) * 32;

  bf16x8 qf0 = *(const bf16x8*)(qb + ((size_t)b*SEQ + qt*16 + m)*HS + g*8);
  bf16x8 qf1 = *(const bf16x8*)(qb + ((size_t)b*SEQ + qt*16 + m)*HS + 32 + g*8);

  const f32x4 vz = {0.f,0.f,0.f,0.f};
  f32x4 o_acc[4] = {vz, vz, vz, vz};   // O^T[d=16nd+4g+i][q=m]
  float mrun = -INFINITY, lrun = 0.f;  // row-uniform state for q-row m

  bf16x8 kp[8], vp[8];
  const bf16* kbB = kb  + (size_t)b*SEQ*HS;
  const bf16* vtB = vtb + (size_t)b*HS*SEQ;

  auto loadKV = [&](int j) {
    const bf16* kt_ = kbB + (size_t)j*64*HS;
    const bf16* vt_ = vtB + j*64;
#pragma unroll
    for (int q = 0; q < 4; ++q) {
      kp[q]   = *(const bf16x8*)(kt_ + (size_t)r0*64        + hh + q*8);
      kp[4+q] = *(const bf16x8*)(kt_ + (size_t)(r0+32)*64   + hh + q*8);
      vp[q]   = *(const bf16x8*)(vt_ + (size_t)r0*SEQ       + hh + q*8);
      vp[4+q] = *(const bf16x8*)(vt_ + (size_t)(r0+32)*SEQ  + hh + q*8);
    }
  };
  auto writeKV = [&]() {
#pragma unroll
    for (int q = 0; q < 4; ++q) {
      *(bf16x8*)&Ks[w][r0][hh + q*8]      = kp[q];
      *(bf16x8*)&Ks[w][r0+32][hh + q*8]   = kp[4+q];
      *(bf16x8*)&VTs[w][r0][hh + q*8]     = vp[q];
      *(bf16x8*)&VTs[w][r0+32][hh + q*8]  = vp[4+q];
    }
  };

  int j = w;
  if (j < nkv) {
    loadKV(j);
    writeKV();
    while (true) {
      const int jn = j + 2;
      const bool more = jn < nkv;
      if (more) loadKV(jn);

      f32x4 s_acc[4];
#pragma unroll
      for (int na = 0; na < 4; ++na) {
        f32x4 z = vz;
        z = MFMA16(*(const bf16x8*)&Ks[w][16*na + m][g*8],      qf0, z);
        z = MFMA16(*(const bf16x8*)&Ks[w][16*na + m][32 + g*8], qf1, z);
        s_acc[na] = z;
      }
      if (j == nkv - 1) {   // causal mask: kv > q
        const int q_ = qt*16 + m;
#pragma unroll
        for (int na = 0; na < 4; ++na)
#pragma unroll
          for (int i = 0; i < 4; ++i)
            if (j*64 + 16*na + 4*g + i > q_) s_acc[na][i] = -INFINITY;
      }

      float mx = fmaxf(
        fmaxf(fmaxf(fmaxf(s_acc[0][0],s_acc[0][1]),fmaxf(s_acc[0][2],s_acc[0][3])),
              fmaxf(fmaxf(s_acc[1][0],s_acc[1][1]),fmaxf(s_acc[1][2],s_acc[1][3]))),
        fmaxf(fmaxf(fmaxf(s_acc[2][0],s_acc[2][1]),fmaxf(s_acc[2][2],s_acc[2][3])),
              fmaxf(fmaxf(s_acc[3][0],s_acc[3][1]),fmaxf(s_acc[3][2],s_acc[3][3]))));
      mx = fmaxf(mx, __shfl_xor(mx, 16));
      mx = fmaxf(mx, __shfl_xor(mx, 32));   // row max over all 64 kv
      float mnew = fmaxf(mrun, mx);
      float corr = __expf(mrun - mnew);
      mrun = mnew;
      float ts = 0.f;
#pragma unroll
      for (int na = 0; na < 4; ++na) {
        bf16x4 pk;
#pragma unroll
        for (int i = 0; i < 4; ++i) {
          float p = __expf(s_acc[na][i] - mnew);
          ts += p;
          pk[i] = (bf16)p;
        }
        *(bf16x4*)&Ps[w][m][16*na + 4*g] = pk;
      }
      ts += __shfl_xor(ts, 16);
      ts += __shfl_xor(ts, 32);
      lrun = lrun * corr + ts;
#pragma unroll
      for (int nd = 0; nd < 4; ++nd)
#pragma unroll
        for (int i = 0; i < 4; ++i) o_acc[nd][i] *= corr;

      bf16x8 pf0 = *(const bf16x8*)&Ps[w][m][g*8];
      bf16x8 pf1 = *(const bf16x8*)&Ps[w][m][32 + g*8];
#pragma unroll
      for (int nd = 0; nd < 4; ++nd) {
        o_acc[nd] = MFMA16(*(const bf16x8*)&VTs[w][16*nd + m][g*8],      pf0, o_acc[nd]);
        o_acc[nd] = MFMA16(*(const bf16x8*)&VTs[w][16*nd + m][32 + g*8], pf1, o_acc[nd]);
      }

      if (!more) break;
      writeKV();
      j = jn;
    }
  }

  float* PO = (float*)&Ks[w][0][0];    // 16 x 68 f32
  float* PM = (float*)&VTs[w][0][0];   // m[16], l[16]
#pragma unroll
  for (int nd = 0; nd < 4; ++nd)
    *(f32x4*)&PO[m*68 + 16*nd + 4*g] = o_acc[nd];
  if (g == 0) { PM[m] = mrun; PM[16 + m] = lrun; }
  __syncthreads();

  {
    const int r  = tid >> 3;
    const int c0 = (tid & 7) * 8;
    const float* O0 = (const float*)&Ks[0][0][0];
    const float* O1 = (const float*)&Ks[1][0][0];
    const float* M0 = (const float*)&VTs[0][0][0];
    const float* M1 = (const float*)&VTs[1][0][0];
    float m0 = M0[r], l0 = M0[16 + r];
    float m1 = M1[r], l1 = M1[16 + r];
    float mx = fmaxf(m0, m1);
    float s0 = __expf(m0 - mx), s1 = __expf(m1 - mx);
    float inv = 1.f / (s0*l0 + s1*l1);
    float4 x0 = *(const float4*)(O0 + r*68 + c0);
    float4 x1 = *(const float4*)(O0 + r*68 + c0 + 4);
    float4 y0 = *(const float4*)(O1 + r*68 + c0);
    float4 y1 = *(const float4*)(O1 + r*68 + c0 + 4);
    float4 o0, o1;
    o0.x=(x0.x*s0+y0.x*s1)*inv; o0.y=(x0.y*s0+y0.y*s1)*inv;
    o0.z=(x0.z*s0+y0.z*s1)*inv; o0.w=(x0.w*s0+y0.w*s1)*inv;
    o1.x=(x1.x*s0+y1.x*s1)*inv; o1.y=(x1.y*s0+y1.y*s1)*inv;
    o1.z=(x1.z*s0+y1.z*s1)*inv; o1.w=(x1.w*s0+y1.w*s1)*inv;
    float* op = out + ((size_t)b*SEQ + qt*16 + r) * HS + c0;
    *(float4*)(op)     = o0;
    *(float4*)(op + 4) = o1;
  }
}

extern "C" void kernel_launch(void* const* d_in, const int* in_sizes, int n_in,
                              void* d_out, int out_size, void* d_ws, size_t ws_size,
                              hipStream_t stream) {
  (void)in_sizes; (void)n_in; (void)out_size; (void)ws_size;
  const float* index  = (const float*)d_in[0];
  const float* memory = (const float*)d_in[1];
  const float* Wq     = (const float*)d_in[2];
  const float* Wk     = (const float*)d_in[3];
  const float* Wv     = (const float*)d_in[4];
  float* out = (float*)d_out;

  bf16* qb  = (bf16*)d_ws;                          // [NB*SEQ][64]
  bf16* kb  = qb  + (size_t)NB * SEQ * HS;          // [NB*SEQ][64]
  bf16* vtb = kb  + (size_t)NB * SEQ * HS;          // [NB][64][SEQ]
  bf16* wqb = vtb + (size_t)NB * SEQ * HS;          // [64][1024] (pre-scaled)
  bf16* wkb = wqb + (size_t)HS * NE;
  bf16* wvb = wkb + (size_t)HS * NE;

  wcvt_kernel<<<dim3(64), 256, 0, stream>>>(Wq, Wk, Wv, wqb, wkb, wvb);
  proj_kernel<<<dim3(512), 256, 0, stream>>>(index, memory, wqb, wkb, wvb, qb, kb, vtb);
  attn_kernel<<<dim3(128, 8), 128, 0, stream>>>(qb, kb, vtb, out);
}

// Round 11
// 72.377 us; speedup vs baseline: 1.0259x; 1.0259x over previous
//
#include <hip/hip_runtime.h>
#include <math.h>

typedef __bf16 bf16;
typedef __bf16 bf16x4 __attribute__((ext_vector_type(4)));
typedef __bf16 bf16x8 __attribute__((ext_vector_type(8)));
typedef float f32x4 __attribute__((ext_vector_type(4)));

#define MFMA16(a,b,c) __builtin_amdgcn_mfma_f32_16x16x32_bf16((a),(b),(c),0,0,0)

static constexpr int HS  = 64;    // head size
static constexpr int SEQ = 2048;  // sequence length
static constexpr int NE  = 1024;  // n_embed
static constexpr int NB  = 8;     // batch

__device__ __forceinline__ bf16x8 cvt8(float4 a, float4 b) {
  bf16x8 r;
  r[0]=(bf16)a.x; r[1]=(bf16)a.y; r[2]=(bf16)a.z; r[3]=(bf16)a.w;
  r[4]=(bf16)b.x; r[5]=(bf16)b.y; r[6]=(bf16)b.z; r[7]=(bf16)b.w;
  return r;
}

// async global->LDS, 16 bytes per lane (lds dest = wave-uniform base + lane*16)
__device__ __forceinline__ void gload16(const void* g, void* l) {
  __builtin_amdgcn_global_load_lds(
      (const __attribute__((address_space(1))) void*)g,
      (__attribute__((address_space(3))) void*)l, 16, 0, 0);
}

// ---- W f32 -> bf16 (Wq pre-scaled by 1/sqrt(64)) ----
__global__ __launch_bounds__(256) void wcvt_kernel(
    const float* __restrict__ Wq, const float* __restrict__ Wk,
    const float* __restrict__ Wv, bf16* __restrict__ wqb,
    bf16* __restrict__ wkb, bf16* __restrict__ wvb)
{
  int i = (blockIdx.x * 256 + threadIdx.x) * 4;   // 64 blocks -> 65536 elems
  float4 q = *(const float4*)(Wq + i);
  float4 k = *(const float4*)(Wk + i);
  float4 v = *(const float4*)(Wv + i);
  bf16x4 qo, ko, vo;
  qo[0]=(bf16)(q.x*0.125f); qo[1]=(bf16)(q.y*0.125f); qo[2]=(bf16)(q.z*0.125f); qo[3]=(bf16)(q.w*0.125f);
  ko[0]=(bf16)k.x; ko[1]=(bf16)k.y; ko[2]=(bf16)k.z; ko[3]=(bf16)k.w;
  vo[0]=(bf16)v.x; vo[1]=(bf16)v.y; vo[2]=(bf16)v.z; vo[3]=(bf16)v.w;
  *(bf16x4*)(wqb + i) = qo;
  *(bf16x4*)(wkb + i) = ko;
  *(bf16x4*)(wvb + i) = vo;
}

// ---- projection: UNIFORM blocks (one output matrix each), 3 blocks/CU ----
// grid 768 x 256thr: blocks [0,256)=q, [256,512)=k, [512,768)=v. Every block
// has identical work: per k-step stage X f32 (16KB) + one W bf16 (8KB) via
// global_load_lds (pre-swizzled source, linear LDS), 8 MFMA/wave. 48KB LDS ->
// 3 blocks/CU; co-resident uniform blocks hide the barrier drains (m97-style).
template<int TRANS>
__device__ __forceinline__ void proj_body(
    const float* __restrict__ X, const bf16* __restrict__ W,
    bf16* __restrict__ outN, bf16* __restrict__ outT, int slab,
    char* Xb, char* Wb)
{
  const int tid  = threadIdx.x;
  const int lane = tid & 63;
  const int w    = tid >> 6;
  const int m    = lane & 15;
  const int g    = lane >> 4;
  const int rowBase = slab * 64;

  const f32x4 vz = {0.f,0.f,0.f,0.f};
  f32x4 acc[4] = {vz, vz, vz, vz};

  const float* Xbase = X + (size_t)rowBase * NE;

  auto stage = [&](int kt, int buf) {
    // X: 4 instrs/thread; instr q covers rows (q*4+w)*4 .. +3 (1024B each)
#pragma unroll
    for (int q = 0; q < 4; ++q) {
      int r = (q*4 + w)*4 + (lane >> 4);
      int s = lane & 15;
      const float* src = Xbase + (size_t)r * NE + kt*64 + ((s ^ (r & 15)) * 4);
      gload16(src, Xb + buf*16384 + (q*4 + w)*1024);   // wave-uniform base
    }
    // W: 2 instrs/thread; instr q covers rows (q*4+w)*8 .. +7
#pragma unroll
    for (int q = 0; q < 2; ++q) {
      int r = (q*4 + w)*8 + (lane >> 3);
      int s = lane & 7;
      size_t soff = (size_t)r * NE + kt*64 + ((s ^ (r & 7)) * 8);
      gload16(W + soff, Wb + buf*8192 + (q*4 + w)*1024);
    }
  };

  auto compute = [&](int buf) {
#pragma unroll
    for (int kk = 0; kk < 2; ++kk) {
      const int arow = 16*w + m;
      const int s0 = 2*(kk*4 + g);
      const char* ab = Xb + buf*16384 + arow*256;
      float4 x0 = *(const float4*)(ab + (( s0      ^ (arow & 15)) * 16));
      float4 x1 = *(const float4*)(ab + (((s0 + 1) ^ (arow & 15)) * 16));
      bf16x8 af = cvt8(x0, x1);
#pragma unroll
      for (int n = 0; n < 4; ++n) {
        const int col = 16*n + m;
        const int ws  = kk*4 + g;
        bf16x8 b0 = *(const bf16x8*)(Wb + buf*8192 + col*128 + ((ws ^ (col & 7)) * 16));
        acc[n] = MFMA16(af, b0, acc[n]);
      }
    }
  };

  stage(0, 0);
  __syncthreads();            // drains stage-0
  int buf = 0;
  for (int kt = 0; kt < 16; ++kt) {
    if (kt + 1 < 16) stage(kt + 1, buf ^ 1);   // async prefetch
    compute(buf);
    __syncthreads();          // drains prefetch + guards LDS reuse
    buf ^= 1;
  }

  // C/D: col = lane&15, row = 4*(lane>>4)+i  [m89-verified]
#pragma unroll
  for (int n = 0; n < 4; ++n)
#pragma unroll
    for (int i = 0; i < 4; ++i) {
      int row = rowBase + 16*w + 4*g + i;
      int h   = 16*n + m;
      if (!TRANS)
        outN[(size_t)row * HS + h] = (bf16)acc[n][i];
      else
        outT[((size_t)(row >> 11) * HS + h) * SEQ + (row & 2047)] =
            (bf16)acc[n][i];
    }
}

__global__ __launch_bounds__(256, 3) void proj_kernel(
    const float* __restrict__ index, const float* __restrict__ memory,
    const bf16* __restrict__ wqb, const bf16* __restrict__ wkb,
    const bf16* __restrict__ wvb, bf16* __restrict__ qb,
    bf16* __restrict__ kb, bf16* __restrict__ vtb)
{
  __shared__ __align__(1024) char Xb[32768];   // f32 X tile, 2 buffers
  __shared__ __align__(1024) char Wb[16384];   // bf16 W tile, 2 buffers (48KB)
  const int bid = blockIdx.x;
  if (bid < 256)
    proj_body<0>(index,  wqb, qb, nullptr, bid,       Xb, Wb);
  else if (bid < 512)
    proj_body<0>(memory, wkb, kb, nullptr, bid - 256, Xb, Wb);
  else
    proj_body<1>(memory, wvb, nullptr, vtb, bid - 512, Xb, Wb);
}

// ---- flash attention: swapped-operand softmax (T12), unchanged from R10 ----
__global__ __launch_bounds__(128) void attn_kernel(
    const bf16* __restrict__ qb, const bf16* __restrict__ kb,
    const bf16* __restrict__ vtb, float* __restrict__ out)
{
  __shared__ __align__(16) bf16 Ks[2][64][72];    // per-wave K tile [kv][d]
  __shared__ __align__(16) bf16 VTs[2][64][72];   // per-wave V^T tile [d][kv]
  __shared__ __align__(16) bf16 Ps[2][16][72];    // per-wave P [q][kv]

  const int tid  = threadIdx.x;
  const int lane = tid & 63;
  const int w    = tid >> 6;
  const int m    = lane & 15;
  const int g    = lane >> 4;
  const int qt   = 127 - blockIdx.x;   // reversed: longest blocks first
  const int b    = blockIdx.y;
  const int nkv  = (qt >> 2) + 1;
  const int r0   = lane >> 1;
  const int hh   = (lane & 1) * 32;

  bf16x8 qf0 = *(const bf16x8*)(qb + ((size_t)b*SEQ + qt*16 + m)*HS + g*8);
  bf16x8 qf1 = *(const bf16x8*)(qb + ((size_t)b*SEQ + qt*16 + m)*HS + 32 + g*8);

  const f32x4 vz = {0.f,0.f,0.f,0.f};
  f32x4 o_acc[4] = {vz, vz, vz, vz};   // O^T[d=16nd+4g+i][q=m]
  float mrun = -INFINITY, lrun = 0.f;  // row-uniform state for q-row m

  bf16x8 kp[8], vp[8];
  const bf16* kbB = kb  + (size_t)b*SEQ*HS;
  const bf16* vtB = vtb + (size_t)b*HS*SEQ;

  auto loadKV = [&](int j) {
    const bf16* kt_ = kbB + (size_t)j*64*HS;
    const bf16* vt_ = vtB + j*64;
#pragma unroll
    for (int q = 0; q < 4; ++q) {
      kp[q]   = *(const bf16x8*)(kt_ + (size_t)r0*64        + hh + q*8);
      kp[4+q] = *(const bf16x8*)(kt_ + (size_t)(r0+32)*64   + hh + q*8);
      vp[q]   = *(const bf16x8*)(vt_ + (size_t)r0*SEQ       + hh + q*8);
      vp[4+q] = *(const bf16x8*)(vt_ + (size_t)(r0+32)*SEQ  + hh + q*8);
    }
  };
  auto writeKV = [&]() {
#pragma unroll
    for (int q = 0; q < 4; ++q) {
      *(bf16x8*)&Ks[w][r0][hh + q*8]      = kp[q];
      *(bf16x8*)&Ks[w][r0+32][hh + q*8]   = kp[4+q];
      *(bf16x8*)&VTs[w][r0][hh + q*8]     = vp[q];
      *(bf16x8*)&VTs[w][r0+32][hh + q*8]  = vp[4+q];
    }
  };

  int j = w;
  if (j < nkv) {
    loadKV(j);
    writeKV();
    while (true) {
      const int jn = j + 2;
      const bool more = jn < nkv;
      if (more) loadKV(jn);

      f32x4 s_acc[4];
#pragma unroll
      for (int na = 0; na < 4; ++na) {
        f32x4 z = vz;
        z = MFMA16(*(const bf16x8*)&Ks[w][16*na + m][g*8],      qf0, z);
        z = MFMA16(*(const bf16x8*)&Ks[w][16*na + m][32 + g*8], qf1, z);
        s_acc[na] = z;
      }
      if (j == nkv - 1) {   // causal mask: kv > q
        const int q_ = qt*16 + m;
#pragma unroll
        for (int na = 0; na < 4; ++na)
#pragma unroll
          for (int i = 0; i < 4; ++i)
            if (j*64 + 16*na + 4*g + i > q_) s_acc[na][i] = -INFINITY;
      }

      float mx = fmaxf(
        fmaxf(fmaxf(fmaxf(s_acc[0][0],s_acc[0][1]),fmaxf(s_acc[0][2],s_acc[0][3])),
              fmaxf(fmaxf(s_acc[1][0],s_acc[1][1]),fmaxf(s_acc[1][2],s_acc[1][3]))),
        fmaxf(fmaxf(fmaxf(s_acc[2][0],s_acc[2][1]),fmaxf(s_acc[2][2],s_acc[2][3])),
              fmaxf(fmaxf(s_acc[3][0],s_acc[3][1]),fmaxf(s_acc[3][2],s_acc[3][3]))));
      mx = fmaxf(mx, __shfl_xor(mx, 16));
      mx = fmaxf(mx, __shfl_xor(mx, 32));   // row max over all 64 kv
      float mnew = fmaxf(mrun, mx);
      float corr = __expf(mrun - mnew);
      mrun = mnew;
      float ts = 0.f;
#pragma unroll
      for (int na = 0; na < 4; ++na) {
        bf16x4 pk;
#pragma unroll
        for (int i = 0; i < 4; ++i) {
          float p = __expf(s_acc[na][i] - mnew);
          ts += p;
          pk[i] = (bf16)p;
        }
        *(bf16x4*)&Ps[w][m][16*na + 4*g] = pk;
      }
      ts += __shfl_xor(ts, 16);
      ts += __shfl_xor(ts, 32);
      lrun = lrun * corr + ts;
#pragma unroll
      for (int nd = 0; nd < 4; ++nd)
#pragma unroll
        for (int i = 0; i < 4; ++i) o_acc[nd][i] *= corr;

      bf16x8 pf0 = *(const bf16x8*)&Ps[w][m][g*8];
      bf16x8 pf1 = *(const bf16x8*)&Ps[w][m][32 + g*8];
#pragma unroll
      for (int nd = 0; nd < 4; ++nd) {
        o_acc[nd] = MFMA16(*(const bf16x8*)&VTs[w][16*nd + m][g*8],      pf0, o_acc[nd]);
        o_acc[nd] = MFMA16(*(const bf16x8*)&VTs[w][16*nd + m][32 + g*8], pf1, o_acc[nd]);
      }

      if (!more) break;
      writeKV();
      j = jn;
    }
  }

  float* PO = (float*)&Ks[w][0][0];    // 16 x 68 f32
  float* PM = (float*)&VTs[w][0][0];   // m[16], l[16]
#pragma unroll
  for (int nd = 0; nd < 4; ++nd)
    *(f32x4*)&PO[m*68 + 16*nd + 4*g] = o_acc[nd];
  if (g == 0) { PM[m] = mrun; PM[16 + m] = lrun; }
  __syncthreads();

  {
    const int r  = tid >> 3;
    const int c0 = (tid & 7) * 8;
    const float* O0 = (const float*)&Ks[0][0][0];
    const float* O1 = (const float*)&Ks[1][0][0];
    const float* M0 = (const float*)&VTs[0][0][0];
    const float* M1 = (const float*)&VTs[1][0][0];
    float m0 = M0[r], l0 = M0[16 + r];
    float m1 = M1[r], l1 = M1[16 + r];
    float mx = fmaxf(m0, m1);
    float s0 = __expf(m0 - mx), s1 = __expf(m1 - mx);
    float inv = 1.f / (s0*l0 + s1*l1);
    float4 x0 = *(const float4*)(O0 + r*68 + c0);
    float4 x1 = *(const float4*)(O0 + r*68 + c0 + 4);
    float4 y0 = *(const float4*)(O1 + r*68 + c0);
    float4 y1 = *(const float4*)(O1 + r*68 + c0 + 4);
    float4 o0, o1;
    o0.x=(x0.x*s0+y0.x*s1)*inv; o0.y=(x0.y*s0+y0.y*s1)*inv;
    o0.z=(x0.z*s0+y0.z*s1)*inv; o0.w=(x0.w*s0+y0.w*s1)*inv;
    o1.x=(x1.x*s0+y1.x*s1)*inv; o1.y=(x1.y*s0+y1.y*s1)*inv;
    o1.z=(x1.z*s0+y1.z*s1)*inv; o1.w=(x1.w*s0+y1.w*s1)*inv;
    float* op = out + ((size_t)b*SEQ + qt*16 + r) * HS + c0;
    *(float4*)(op)     = o0;
    *(float4*)(op + 4) = o1;
  }
}

extern "C" void kernel_launch(void* const* d_in, const int* in_sizes, int n_in,
                              void* d_out, int out_size, void* d_ws, size_t ws_size,
                              hipStream_t stream) {
  (void)in_sizes; (void)n_in; (void)out_size; (void)ws_size;
  const float* index  = (const float*)d_in[0];
  const float* memory = (const float*)d_in[1];
  const float* Wq     = (const float*)d_in[2];
  const float* Wk     = (const float*)d_in[3];
  const float* Wv     = (const float*)d_in[4];
  float* out = (float*)d_out;

  bf16* qb  = (bf16*)d_ws;                          // [NB*SEQ][64]
  bf16* kb  = qb  + (size_t)NB * SEQ * HS;          // [NB*SEQ][64]
  bf16* vtb = kb  + (size_t)NB * SEQ * HS;          // [NB][64][SEQ]
  bf16* wqb = vtb + (size_t)NB * SEQ * HS;          // [64][1024] (pre-scaled)
  bf16* wkb = wqb + (size_t)HS * NE;
  bf16* wvb = wkb + (size_t)HS * NE;

  wcvt_kernel<<<dim3(64), 256, 0, stream>>>(Wq, Wk, Wv, wqb, wkb, wvb);
  proj_kernel<<<dim3(768), 256, 0, stream>>>(index, memory, wqb, wkb, wvb, qb, kb, vtb);
  attn_kernel<<<dim3(128, 8), 128, 0, stream>>>(qb, kb, vtb, out);
}